// Round 3
// baseline (101.921 us; speedup 1.0000x reference)
//
#include <hip/hip_runtime.h>
#include <hip/hip_bf16.h>

#define NB 2048     // batch rows
#define NL 64       // latent dim
#define NN 16       // nuisance dim
#define NROW 80     // NL + NN (z row length)
#define NO 2048     // output dim
#define TPB 256     // threads per block (4 waves)
#define OPT 8       // outputs per thread (2048/256)

typedef unsigned int   u32;
typedef unsigned short u16;

// bf16 (in low/high half of a u32) -> f32
__device__ __forceinline__ float bflo(u32 u) { union { u32 i; float f; } c; c.i = u << 16;          return c.f; }
__device__ __forceinline__ float bfhi(u32 u) { union { u32 i; float f; } c; c.i = u & 0xffff0000u;  return c.f; }
__device__ __forceinline__ u16 f2bf(float f) { __hip_bfloat16 h = __float2bfloat16(f); return *(u16*)&h; }

// ---- Pass 1: M[id][l][o] = bf16(W[l][o] + A[id][l][o]), 16*64*2048 elems ----
__global__ __launch_bounds__(TPB) void build_m(const float* __restrict__ W,
                                               const float* __restrict__ A,
                                               u16* __restrict__ M) {
    size_t t    = (size_t)blockIdx.x * TPB + threadIdx.x;
    size_t base = t * 4;                                  // 4 floats per thread
    float4 w = *(const float4*)(W + (base & (size_t)(NL * NO - 1)));  // W idx = base mod 64*2048
    float4 a = *(const float4*)(A + base);
    ushort4 m;
    m.x = f2bf(w.x + a.x);
    m.y = f2bf(w.y + a.y);
    m.z = f2bf(w.z + a.z);
    m.w = f2bf(w.w + a.w);
    *(ushort4*)(M + base) = m;
}

// ---- Pass 2: per-row logits from bf16 M, softmax, scale, store FP32 ----
__global__ __launch_bounds__(TPB) void decoder_m(
    const float* __restrict__ z,     // (2048, 80)  f32
    const float* __restrict__ sf,    // (2048, 1)   f32
    const u16*   __restrict__ M,     // (16, 64, 2048) bf16 (precomputed W+A)
    const float* __restrict__ offs,  // (16, 2048)  f32
    const float* __restrict__ pxr,   // (2048,)     f32
    float* __restrict__ out)         // mu (2048*2048) ++ theta (2048), FP32
{
    const int b   = blockIdx.x;
    const int tid = threadIdx.x;

    if (b == NB) {  // theta = exp(px_r)
        for (int o = tid; o < NO; o += TPB)
            out[(size_t)NB * NO + o] = __expf(pxr[o]);
        return;
    }

    __shared__ float z0s[NL];
    __shared__ int   s_id;
    __shared__ float s_red[6];

    if (tid < NL) z0s[tid] = z[b * NROW + tid];
    if (tid == 0) {
        float best = -1e30f; int bi = 0;
        for (int i = 0; i < NN; ++i) {
            float v = z[b * NROW + NL + i];
            if (v > best) { best = v; bi = i; }   // strict > = first-max tie-break (numpy)
        }
        s_id = bi;
    }
    __syncthreads();
    const int id = s_id;

    const int o0 = tid * OPT;
    const uint4* mv = (const uint4*)(M + (size_t)id * NL * NO + o0);

    float acc[OPT];
    {
        float4 oa = *(const float4*)(offs + id * NO + o0);
        float4 ob = *(const float4*)(offs + id * NO + o0 + 4);
        acc[0] = oa.x; acc[1] = oa.y; acc[2] = oa.z; acc[3] = oa.w;
        acc[4] = ob.x; acc[5] = ob.y; acc[6] = ob.z; acc[7] = ob.w;
    }

    #pragma unroll 8
    for (int l = 0; l < NL; ++l) {
        const float zl = z0s[l];
        uint4 m = mv[l * (NO / OPT)];
        acc[0] += zl * bflo(m.x); acc[1] += zl * bfhi(m.x);
        acc[2] += zl * bflo(m.y); acc[3] += zl * bfhi(m.y);
        acc[4] += zl * bflo(m.z); acc[5] += zl * bfhi(m.z);
        acc[6] += zl * bflo(m.w); acc[7] += zl * bfhi(m.w);
    }

    // ---- block softmax over 2048 outputs ----
    float m = acc[0];
    #pragma unroll
    for (int j = 1; j < OPT; ++j) m = fmaxf(m, acc[j]);
    #pragma unroll
    for (int off = 32; off > 0; off >>= 1) m = fmaxf(m, __shfl_down(m, off));
    if ((tid & 63) == 0) s_red[tid >> 6] = m;
    __syncthreads();
    if (tid == 0) s_red[4] = fmaxf(fmaxf(s_red[0], s_red[1]), fmaxf(s_red[2], s_red[3]));
    __syncthreads();
    const float mx = s_red[4];

    float ex[OPT];
    float s = 0.f;
    #pragma unroll
    for (int j = 0; j < OPT; ++j) { ex[j] = __expf(acc[j] - mx); s += ex[j]; }
    #pragma unroll
    for (int off = 32; off > 0; off >>= 1) s += __shfl_down(s, off);
    if ((tid & 63) == 0) s_red[tid >> 6] = s;
    __syncthreads();
    if (tid == 0) s_red[5] = (s_red[0] + s_red[1]) + (s_red[2] + s_red[3]);
    __syncthreads();
    const float scale = sf[b] / s_red[5];

    float* op = out + (size_t)b * NO + o0;
    *(float4*)(op)     = make_float4(ex[0] * scale, ex[1] * scale, ex[2] * scale, ex[3] * scale);
    *(float4*)(op + 4) = make_float4(ex[4] * scale, ex[5] * scale, ex[6] * scale, ex[7] * scale);
}

// ---- Fallback (ws too small): direct fp32 W/A reads, FP32 out ----
__global__ __launch_bounds__(TPB) void decoder_f(
    const float* __restrict__ z, const float* __restrict__ sf,
    const float* __restrict__ W, const float* __restrict__ A,
    const float* __restrict__ offs, const float* __restrict__ pxr,
    float* __restrict__ out)
{
    const int b   = blockIdx.x;
    const int tid = threadIdx.x;
    if (b == NB) {
        for (int o = tid; o < NO; o += TPB)
            out[(size_t)NB * NO + o] = __expf(pxr[o]);
        return;
    }
    __shared__ float z0s[NL];
    __shared__ int   s_id;
    __shared__ float s_red[6];
    if (tid < NL) z0s[tid] = z[b * NROW + tid];
    if (tid == 0) {
        float best = -1e30f; int bi = 0;
        for (int i = 0; i < NN; ++i) {
            float v = z[b * NROW + NL + i];
            if (v > best) { best = v; bi = i; }
        }
        s_id = bi;
    }
    __syncthreads();
    const int id = s_id;
    const int o0 = tid * OPT;
    const float* wp = W + o0;
    const float* ap = A + (size_t)id * NL * NO + o0;
    float acc[OPT];
    {
        float4 oa = *(const float4*)(offs + id * NO + o0);
        float4 ob = *(const float4*)(offs + id * NO + o0 + 4);
        acc[0] = oa.x; acc[1] = oa.y; acc[2] = oa.z; acc[3] = oa.w;
        acc[4] = ob.x; acc[5] = ob.y; acc[6] = ob.z; acc[7] = ob.w;
    }
    #pragma unroll 4
    for (int l = 0; l < NL; ++l) {
        const float zl = z0s[l];
        float4 w0 = *(const float4*)(wp + l * NO);
        float4 w1 = *(const float4*)(wp + l * NO + 4);
        float4 a0 = *(const float4*)(ap + l * NO);
        float4 a1 = *(const float4*)(ap + l * NO + 4);
        acc[0] += zl * (w0.x + a0.x); acc[1] += zl * (w0.y + a0.y);
        acc[2] += zl * (w0.z + a0.z); acc[3] += zl * (w0.w + a0.w);
        acc[4] += zl * (w1.x + a1.x); acc[5] += zl * (w1.y + a1.y);
        acc[6] += zl * (w1.z + a1.z); acc[7] += zl * (w1.w + a1.w);
    }
    float m = acc[0];
    #pragma unroll
    for (int j = 1; j < OPT; ++j) m = fmaxf(m, acc[j]);
    #pragma unroll
    for (int off = 32; off > 0; off >>= 1) m = fmaxf(m, __shfl_down(m, off));
    if ((tid & 63) == 0) s_red[tid >> 6] = m;
    __syncthreads();
    if (tid == 0) s_red[4] = fmaxf(fmaxf(s_red[0], s_red[1]), fmaxf(s_red[2], s_red[3]));
    __syncthreads();
    const float mx = s_red[4];
    float ex[OPT];
    float s = 0.f;
    #pragma unroll
    for (int j = 0; j < OPT; ++j) { ex[j] = __expf(acc[j] - mx); s += ex[j]; }
    #pragma unroll
    for (int off = 32; off > 0; off >>= 1) s += __shfl_down(s, off);
    if ((tid & 63) == 0) s_red[tid >> 6] = s;
    __syncthreads();
    if (tid == 0) s_red[5] = (s_red[0] + s_red[1]) + (s_red[2] + s_red[3]);
    __syncthreads();
    const float scale = sf[b] / s_red[5];
    float* op = out + (size_t)b * NO + o0;
    *(float4*)(op)     = make_float4(ex[0] * scale, ex[1] * scale, ex[2] * scale, ex[3] * scale);
    *(float4*)(op + 4) = make_float4(ex[4] * scale, ex[5] * scale, ex[6] * scale, ex[7] * scale);
}

extern "C" void kernel_launch(void* const* d_in, const int* in_sizes, int n_in,
                              void* d_out, int out_size, void* d_ws, size_t ws_size,
                              hipStream_t stream) {
    const float* z    = (const float*)d_in[0];
    const float* sf   = (const float*)d_in[1];
    const float* W    = (const float*)d_in[2];
    const float* A    = (const float*)d_in[3];
    const float* offs = (const float*)d_in[4];
    const float* pxr  = (const float*)d_in[5];
    float* out = (float*)d_out;

    const size_t m_bytes = (size_t)NN * NL * NO * sizeof(u16);  // 4 MiB
    if (ws_size >= m_bytes) {
        u16* M = (u16*)d_ws;
        hipLaunchKernelGGL(build_m, dim3((NN * NL * NO / 4) / TPB), dim3(TPB), 0, stream, W, A, M);
        hipLaunchKernelGGL(decoder_m, dim3(NB + 1), dim3(TPB), 0, stream, z, sf, M, offs, pxr, out);
    } else {
        hipLaunchKernelGGL(decoder_f, dim3(NB + 1), dim3(TPB), 0, stream, z, sf, W, A, offs, pxr, out);
    }
}